// Round 8
// baseline (1974.722 us; speedup 1.0000x reference)
//
#include <hip/hip_runtime.h>
#include <stdint.h>

#define B_   64
#define T_   512
#define NIN_ 256
#define N_   512
#define ROWU 260   // th row stride in u32

typedef _Float16 half8   __attribute__((ext_vector_type(8)));
typedef float    f32x4   __attribute__((ext_vector_type(4)));
typedef _Float16 half2_t __attribute__((ext_vector_type(2)));

__device__ __forceinline__ float fast_tanh(float x) {
  float e = __expf(2.0f * x);
  return 1.0f - 2.0f / (e + 1.0f);
}
__device__ __forceinline__ unsigned int packh2(float a, float b) {
  half2_t h; h[0] = (_Float16)a; h[1] = (_Float16)b;
  return __builtin_bit_cast(unsigned int, h);
}

// ---------------- Phase 1: xp[b,t,n] = sum_c x[b,t,c] * Wih[n,c] -> out ----
__global__ __launch_bounds__(256) void xproj(const float* __restrict__ x,
                                             const float* __restrict__ Wih,
                                             float* __restrict__ out) {
  const int tid = threadIdx.x;
  const int bm = blockIdx.x;
  const int bn = blockIdx.y;
  const int tm = tid & 15;
  const int tn = tid >> 4;
  const int m0 = bm << 7;
  const int n0 = bn << 7;

  __shared__ float xt[32][132];
  __shared__ float wt[32][132];

  float acc[8][8];
#pragma unroll
  for (int i = 0; i < 8; ++i)
#pragma unroll
    for (int j = 0; j < 8; ++j) acc[i][j] = 0.f;

  for (int ko = 0; ko < NIN_; ko += 32) {
#pragma unroll
    for (int it = 0; it < 4; ++it) {
      const int fidx = it * 256 + tid;
      const int mm = fidx >> 3;
      const int k4 = (fidx & 7) << 2;
      const float4 vx = *(const float4*)(x + (size_t)(m0 + mm) * NIN_ + ko + k4);
      xt[k4 + 0][mm] = vx.x; xt[k4 + 1][mm] = vx.y;
      xt[k4 + 2][mm] = vx.z; xt[k4 + 3][mm] = vx.w;
      const float4 vw = *(const float4*)(Wih + (size_t)(n0 + mm) * NIN_ + ko + k4);
      wt[k4 + 0][mm] = vw.x; wt[k4 + 1][mm] = vw.y;
      wt[k4 + 2][mm] = vw.z; wt[k4 + 3][mm] = vw.w;
    }
    __syncthreads();
#pragma unroll 4
    for (int kk = 0; kk < 32; ++kk) {
      float a[8], b[8];
      *(float4*)&a[0] = *(const float4*)&xt[kk][8 * tm];
      *(float4*)&a[4] = *(const float4*)&xt[kk][8 * tm + 4];
      *(float4*)&b[0] = *(const float4*)&wt[kk][8 * tn];
      *(float4*)&b[4] = *(const float4*)&wt[kk][8 * tn + 4];
#pragma unroll
      for (int i = 0; i < 8; ++i)
#pragma unroll
        for (int j = 0; j < 8; ++j) acc[i][j] = fmaf(a[i], b[j], acc[i][j]);
    }
    __syncthreads();
  }

#pragma unroll
  for (int i = 0; i < 8; ++i) {
    float4 v0 = make_float4(acc[i][0], acc[i][1], acc[i][2], acc[i][3]);
    float4 v1 = make_float4(acc[i][4], acc[i][5], acc[i][6], acc[i][7]);
    float* p = out + (size_t)(m0 + 8 * tm + i) * N_ + n0 + 8 * tn;
    *(float4*)p = v0;
    *((float4*)p + 1) = v1;
  }
}

// ---------------- Phase 2: MFMA recurrent scan ----------------------------
// 256 blocks x 512 thr; runtime XCD registration (R7-proven). Group = 8
// same-XCD blocks, 8 batches, slice = 64 neurons. Waves 0-3: one 16x16x32
// f16 MFMA tile each; 16 A-fragments in half8 regs PINNED via asm opacity
// (blocks rematerialization -> resident). Waves 4-7: stagers. Exchange:
// producers dual-publish (volatile store -> same-XCD L2 fast path; agent
// atomic store -> L3 guaranteed); consumers volatile-poll with sticky
// bounded fallback to agent loads. Placement-independent correctness.
__global__ __launch_bounds__(512, 1) void rnn_scan(
    const float* __restrict__ Whh, float* __restrict__ out,
    unsigned long long* __restrict__ ex, int* __restrict__ ctrl) {
  const int tid = threadIdx.x;
  const int wv = tid >> 6;
  const int l  = tid & 63;

  __shared__ __align__(16) unsigned int th[2][16][ROWU];
  __shared__ int bcastg, bcasts;

  // ---- registration: discover physical XCD, claim (group, slice) ----
  if (tid == 0) {
    const int xcd = __builtin_amdgcn_s_getreg((31 << 11) | 20) & 7;  // HW_REG_XCC_ID
    const int slot = __hip_atomic_fetch_add(&ctrl[xcd], 1, __ATOMIC_RELAXED,
                                            __HIP_MEMORY_SCOPE_AGENT);
    int srank = -1;
    if (slot >= 8)
      srank = __hip_atomic_fetch_add(&ctrl[8], 1, __ATOMIC_RELAXED,
                                     __HIP_MEMORY_SCOPE_AGENT);
    __hip_atomic_fetch_add(&ctrl[9], 1, __ATOMIC_RELEASE,
                           __HIP_MEMORY_SCOPE_AGENT);
    while (__hip_atomic_load(&ctrl[9], __ATOMIC_ACQUIRE,
                             __HIP_MEMORY_SCOPE_AGENT) != (int)gridDim.x)
      __builtin_amdgcn_s_sleep(1);
    int g = -1, s = -1;
    if (slot < 8) {
      g = xcd; s = slot;
    } else {
      int r = srank;
#pragma unroll
      for (int xx = 0; xx < 8; ++xx) {
        const int c = __hip_atomic_load(&ctrl[xx], __ATOMIC_RELAXED,
                                        __HIP_MEMORY_SCOPE_AGENT);
        const int filled = c < 8 ? c : 8;
        const int d = 8 - filled;
        if (g < 0 && r < d) { g = xx; s = filled + r; }
        if (g < 0) r -= d;
      }
    }
    bcastg = g; bcasts = s;
  }
  __syncthreads();
  const int g = bcastg;
  const int m = bcasts;
  if (g < 0) return;   // surplus block, no leftover work

  // ---- weight A-fragments: 16 half8, loaded by ALL waves, asm-PINNED ----
  const int bc = l & 15;    // A-row / D-col
  const int ko = l >> 4;    // k-octet
  const int arow = m * 64 + (wv & 3) * 16 + bc;
  const float* wbase = Whh + (size_t)arow * N_ + ko * 8;
#define LDW(KS)                                                        \
  half8 wf##KS;                                                        \
  {                                                                    \
    const float* wr = wbase + (KS) * 32;                               \
    const float4 w0 = *(const float4*)wr;                              \
    const float4 w1 = *(const float4*)(wr + 4);                        \
    wf##KS[0] = (_Float16)w0.x; wf##KS[1] = (_Float16)w0.y;            \
    wf##KS[2] = (_Float16)w0.z; wf##KS[3] = (_Float16)w0.w;            \
    wf##KS[4] = (_Float16)w1.x; wf##KS[5] = (_Float16)w1.y;            \
    wf##KS[6] = (_Float16)w1.z; wf##KS[7] = (_Float16)w1.w;            \
  }
  LDW(0) LDW(1) LDW(2) LDW(3) LDW(4) LDW(5) LDW(6) LDW(7)
  LDW(8) LDW(9) LDW(10) LDW(11) LDW(12) LDW(13) LDW(14) LDW(15)
#undef LDW
  // Opacity pin: values no longer traceable to loads -> no remat, no sink.
  asm volatile("" : "+v"(wf0), "+v"(wf1), "+v"(wf2), "+v"(wf3),
                    "+v"(wf4), "+v"(wf5), "+v"(wf6), "+v"(wf7));
  asm volatile("" : "+v"(wf8), "+v"(wf9), "+v"(wf10), "+v"(wf11),
                    "+v"(wf12), "+v"(wf13), "+v"(wf14), "+v"(wf15));

  // ---- init LDS: zero rows 8..15 (both slots), stage tanh(h_1) rows 0..7 --
  for (int i = tid; i < 2 * 8 * ROWU; i += 512) {
    const int slot = i / (8 * ROWU);
    const int r = (i / ROWU) & 7;
    const int c = i % ROWU;
    th[slot][8 + r][c] = 0u;
  }
  for (int i = tid; i < 2048; i += 512) {
    const int b = i >> 8;
    const int c = i & 255;
    const float2 h0 = *(const float2*)(out + (size_t)(g * 8 + b) * T_ * N_ + 2 * c);
    th[0][b][c] = packh2(fast_tanh(h0.x), fast_tanh(h0.y));
  }
  __syncthreads();

  // ---- per-role constants ----
  const int gb = g * 8 + bc;                       // global batch (valid bc<8)
  const int n0 = m * 64 + (wv & 3) * 16 + ko * 4;  // first D-row neuron
  const int np0 = (wv & 3) * 8 + ko * 2;           // pair idx within slice
  const size_t outrow = (size_t)gb * T_ * N_;

  const int lam = tid - 256;                       // stager lane 0..255
  const int sb  = lam >> 5;                        // batch row 0..7
  const int snp = lam & 31;                        // pair col 0..31
  int mrs[7];
#pragma unroll
  for (int i = 0; i < 7; ++i) mrs[i] = i + (i >= m ? 1 : 0);
  bool fastok = true;                              // sticky fast-path flag

  for (int t = 1; t < T_; ++t) {
    if (wv < 4) {
      // ---- compute: one 16x16x32 f16 MFMA tile (two half-K chains) ----
      float4 xp = make_float4(0.f, 0.f, 0.f, 0.f);
      if (bc < 8) xp = *(const float4*)(out + outrow + (size_t)t * N_ + n0);

      const unsigned int* tb = &th[(t - 1) & 1][bc][0];
      f32x4 a0 = {0.f, 0.f, 0.f, 0.f};
      f32x4 a1 = {0.f, 0.f, 0.f, 0.f};
#define MM(KS, KS2)                                                        \
  {                                                                        \
    const uint4 b0 = *(const uint4*)(tb + (KS) * 16 + ko * 4);             \
    const uint4 b1 = *(const uint4*)(tb + (KS2) * 16 + ko * 4);            \
    a0 = __builtin_amdgcn_mfma_f32_16x16x32_f16(                           \
        wf##KS, __builtin_bit_cast(half8, b0), a0, 0, 0, 0);               \
    a1 = __builtin_amdgcn_mfma_f32_16x16x32_f16(                           \
        wf##KS2, __builtin_bit_cast(half8, b1), a1, 0, 0, 0);              \
  }
      MM(0, 8) MM(1, 9) MM(2, 10) MM(3, 11)
      MM(4, 12) MM(5, 13) MM(6, 14) MM(7, 15)
#undef MM
      const f32x4 acc = a0 + a1;

      if (bc < 8) {
        const float y0 = acc[0] + xp.x;
        const float y1 = acc[1] + xp.y;
        const float y2 = acc[2] + xp.z;
        const float y3 = acc[3] + xp.w;
        const unsigned int p0 = packh2(fast_tanh(y0), fast_tanh(y1));
        const unsigned int p1 = packh2(fast_tanh(y2), fast_tanh(y3));
        const size_t eb =
            ((((size_t)g * 2 + (t & 1)) * 8 + m) * 8 + bc) * 32 + np0;
        const unsigned long long tg = (unsigned long long)(unsigned int)t << 32;
        const unsigned long long v0 = tg | p0, v1 = tg | p1;
        // dual publish: volatile (same-XCD L2, fast) + agent atomic (L3, sure)
        volatile unsigned long long* fx = (volatile unsigned long long*)&ex[eb];
        fx[0] = v0;
        fx[1] = v1;
        __hip_atomic_store(&ex[eb], v0, __ATOMIC_RELAXED,
                           __HIP_MEMORY_SCOPE_AGENT);
        __hip_atomic_store(&ex[eb + 1], v1, __ATOMIC_RELAXED,
                           __HIP_MEMORY_SCOPE_AGENT);
        th[t & 1][bc][m * 32 + np0]     = p0;
        th[t & 1][bc][m * 32 + np0 + 1] = p1;
        *(float4*)(out + outrow + (size_t)t * N_ + n0) =
            make_float4(y0, y1, y2, y3);
      }
    } else if (t < T_ - 1) {
      // ---- stagers: 7 remote packets; volatile poll, sticky fallback ----
      const unsigned long long* ap[7];
#pragma unroll
      for (int i = 0; i < 7; ++i)
        ap[i] = &ex[((((size_t)g * 2 + (t & 1)) * 8 + mrs[i]) * 8 + sb) * 32 + snp];
      unsigned int got = 0;
      int rounds = 0;
      do {
#pragma unroll
        for (int i = 0; i < 7; ++i) {
          if (got & (1u << i)) continue;
          const unsigned long long v =
              fastok ? *(volatile const unsigned long long*)ap[i]
                     : __hip_atomic_load(ap[i], __ATOMIC_RELAXED,
                                         __HIP_MEMORY_SCOPE_AGENT);
          if ((unsigned int)(v >> 32) == (unsigned int)t) {
            got |= 1u << i;
            th[t & 1][sb][mrs[i] * 32 + snp] = (unsigned int)v;
          }
        }
        if (++rounds > 512) fastok = false;   // sticky: L3 path from now on
      } while (got != 0x7Fu);
    }
    __syncthreads();   // publishes th[t&1] (own + staged remote) for t+1
  }
}

extern "C" void kernel_launch(void* const* d_in, const int* in_sizes, int n_in,
                              void* d_out, int out_size, void* d_ws, size_t ws_size,
                              hipStream_t stream) {
  const float* x   = (const float*)d_in[0];
  const float* Wih = (const float*)d_in[1];
  const float* Whh = (const float*)d_in[2];
  float* out = (float*)d_out;
  unsigned long long* ex = (unsigned long long*)d_ws;   // 256 KiB exchange
  int* ctrl = (int*)((char*)d_ws + 262144);             // cnt[8], surplus, done

  hipMemsetAsync(d_ws, 0, 262144 + 64, stream);
  dim3 g1(256, 4);
  xproj<<<g1, 256, 0, stream>>>(x, Wih, out);
  rnn_scan<<<256, 512, 0, stream>>>(Whh, out, ex, ctrl);
}

// Round 10
// 1573.697 us; speedup vs baseline: 1.2548x; 1.2548x over previous
//
#include <hip/hip_runtime.h>
#include <stdint.h>

#define B_   64
#define T_   512
#define NIN_ 256
#define N_   512

typedef _Float16 half8   __attribute__((ext_vector_type(8)));
typedef float    f32x4   __attribute__((ext_vector_type(4)));
typedef _Float16 half2_t __attribute__((ext_vector_type(2)));

__device__ __forceinline__ float fast_tanh(float x) {
  float e = __expf(2.0f * x);
  return 1.0f - 2.0f / (e + 1.0f);
}
__device__ __forceinline__ unsigned int packh2(float a, float b) {
  half2_t h; h[0] = (_Float16)a; h[1] = (_Float16)b;
  return __builtin_bit_cast(unsigned int, h);
}

// Fused kernel, 256 blocks x 1024 threads.
//   blocks 0..127  : xproj GEMM (xp -> out), t-chunk-major, release-fenced flags
//   blocks 128..255: scan. group g (4 batches) x slice m (64 neurons).
// Scan: 16 waves, wave wv -> (nr = wv>>2: 16-neuron row, kq = wv&3: 128-k
// quarter). Per step: 1-addr/lane tagged-u64 poll (R4-proven) -> barrier ->
// 4 chained 16x16x32 f16 MFMA (A pinned in VGPR, B = LDS batch-replicated
// broadcast) -> pacc reduce -> 256-lane epilogue (y, tanh, publish-first).
__global__ __launch_bounds__(1024, 4) void rnn_fused(
    const float* __restrict__ x, const float* __restrict__ Wih,
    const float* __restrict__ Whh, float* __restrict__ out,
    unsigned long long* __restrict__ ex, int* __restrict__ ctrl) {
  const int blk = blockIdx.x;
  const int tid = threadIdx.x;

  __shared__ float xt[32][132];
  __shared__ float wt[32][132];
  __shared__ __align__(16) unsigned int th_lds[2][4][260];  // [slot][batch][pair]
  __shared__ __align__(16) float pacc[4][4][16][4];         // [nr][b][row][kq]

  if (blk < 128) {
    // ================= xproj role =================
    const int tm = tid & 15;     // 8-row group
    const int tn = tid >> 4;     // 0..63 -> 2 cols
    for (int tau = blk; tau < 1024; tau += 128) {
      const int tc = tau >> 8;   // t-chunk; each block does chunk-0 tiles first
      const int j  = tau & 255;
      const int bb = j >> 2;
      const int bn = j & 3;
      const int m0 = (bb * 4 + tc) << 7;
      const int nn0 = bn << 7;

      float acc[8][2];
#pragma unroll
      for (int i = 0; i < 8; ++i) { acc[i][0] = 0.f; acc[i][1] = 0.f; }

      for (int ko = 0; ko < NIN_; ko += 32) {
        const int mm = tid >> 3;            // 0..127
        const int k4 = (tid & 7) << 2;      // 0..28
        const float4 vx = *(const float4*)(x + (size_t)(m0 + mm) * NIN_ + ko + k4);
        xt[k4 + 0][mm] = vx.x; xt[k4 + 1][mm] = vx.y;
        xt[k4 + 2][mm] = vx.z; xt[k4 + 3][mm] = vx.w;
        const float4 vw = *(const float4*)(Wih + (size_t)(nn0 + mm) * NIN_ + ko + k4);
        wt[k4 + 0][mm] = vw.x; wt[k4 + 1][mm] = vw.y;
        wt[k4 + 2][mm] = vw.z; wt[k4 + 3][mm] = vw.w;
        __syncthreads();
#pragma unroll 4
        for (int kk = 0; kk < 32; ++kk) {
          float a[8];
          *(float4*)&a[0] = *(const float4*)&xt[kk][8 * tm];
          *(float4*)&a[4] = *(const float4*)&xt[kk][8 * tm + 4];
          const float2 bv = *(const float2*)&wt[kk][2 * tn];
#pragma unroll
          for (int i = 0; i < 8; ++i) {
            acc[i][0] = fmaf(a[i], bv.x, acc[i][0]);
            acc[i][1] = fmaf(a[i], bv.y, acc[i][1]);
          }
        }
        __syncthreads();
      }
#pragma unroll
      for (int i = 0; i < 8; ++i) {
        float2 st; st.x = acc[i][0]; st.y = acc[i][1];
        *(float2*)(out + (size_t)(m0 + 8 * tm + i) * N_ + nn0 + 2 * tn) = st;
      }
      __threadfence();
      __syncthreads();
      if (tid == 0)
        __hip_atomic_fetch_add(&ctrl[tc], 1, __ATOMIC_RELEASE,
                               __HIP_MEMORY_SCOPE_AGENT);
    }
    return;
  }

  // ================= scan role =================
  const int beta = blk - 128;
  const int g = beta & 15;       // group: batches g*4 .. g*4+3
  const int m = beta >> 4;       // slice: neurons m*64 .. m*64+63
  const int gB = g * 4;
  const int ns = m * 64;

  const int wv = tid >> 6;
  const int l  = tid & 63;
  const int nr = wv >> 2;        // 16-neuron row within slice
  const int kq = wv & 3;         // 128-k quarter
  const int c  = l & 15;         // B/D col; batch = c&3 (replicated)
  const int o  = l >> 4;         // k-octet

  // ---- A-fragments: 4 named half8, loaded uniformly, asm-pinned ----
  const int arow = ns + nr * 16 + c;            // neuron of my A-row
  const float* wb = Whh + (size_t)arow * N_ + kq * 128 + o * 8;
#define LDW(TAU)                                                       \
  half8 wf##TAU;                                                       \
  {                                                                    \
    const float* wr = wb + (TAU) * 32;                                 \
    const float4 w0 = *(const float4*)wr;                              \
    const float4 w1 = *(const float4*)(wr + 4);                        \
    wf##TAU[0] = (_Float16)w0.x; wf##TAU[1] = (_Float16)w0.y;          \
    wf##TAU[2] = (_Float16)w0.z; wf##TAU[3] = (_Float16)w0.w;          \
    wf##TAU[4] = (_Float16)w1.x; wf##TAU[5] = (_Float16)w1.y;          \
    wf##TAU[6] = (_Float16)w1.z; wf##TAU[7] = (_Float16)w1.w;          \
  }
  LDW(0) LDW(1) LDW(2) LDW(3)
#undef LDW
  asm volatile("" : "+v"(wf0), "+v"(wf1), "+v"(wf2), "+v"(wf3));

  // ---- role constants ----
  // epilogue (tid<256): (enr, eb, erow)
  const int enr = tid >> 6;            // valid for tid<256
  const int eb  = (tid >> 4) & 3;
  const int erow = tid & 15;
  const size_t outrow_e = (size_t)(gB + eb) * T_ * N_;
  const int eneuron = ns + enr * 16 + erow;
  // poller (tid<896): one remote (slice, batch, pair)
  const int rm = tid >> 7;             // 0..6 (tid<896)
  const int rr = tid & 127;
  const int pb = rr >> 5;              // 0..3
  const int pp = rr & 31;              // 0..31
  const int sm = rm + (rm >= m ? 1 : 0);

  // ---- gate on xproj chunk 0, then init th_lds[0] from h_1 ----
  if (tid == 0) {
    while (__hip_atomic_load(&ctrl[0], __ATOMIC_ACQUIRE,
                             __HIP_MEMORY_SCOPE_AGENT) < 256)
      __builtin_amdgcn_s_sleep(1);
  }
  __syncthreads();
  {
    const int b0 = tid >> 8;           // 0..3
    const int c0 = tid & 255;          // pair 0..255
    const float2 h0 = *(const float2*)(out + (size_t)(gB + b0) * T_ * N_ + 2 * c0);
    th_lds[0][b0][c0] = packh2(fast_tanh(h0.x), fast_tanh(h0.y));
  }
  __syncthreads();

  for (int t = 1; t < T_; ++t) {
    if ((t & 127) == 0) {              // xp chunk gate (t = 128, 256, 384)
      if (tid == 0) {
        while (__hip_atomic_load(&ctrl[t >> 7], __ATOMIC_ACQUIRE,
                                 __HIP_MEMORY_SCOPE_AGENT) < 256)
          __builtin_amdgcn_s_sleep(1);
      }
      __syncthreads();
    }

    // xp prefetch (epilogue lanes; consumed after barrier B)
    float xp = 0.f;
    if (tid < 256) xp = out[outrow_e + (size_t)t * N_ + eneuron];

    // poll ONE remote packet (tag t-1), stage payload
    if (t >= 2 && tid < 896) {
      const unsigned long long* ap =
          &ex[((((size_t)g * 2 + ((t - 1) & 1)) * 8 + sm) * 4 + pb) * 32 + pp];
      unsigned long long v;
      do {
        v = __hip_atomic_load(ap, __ATOMIC_RELAXED, __HIP_MEMORY_SCOPE_AGENT);
      } while ((unsigned int)(v >> 32) != (unsigned int)(t - 1));
      th_lds[(t - 1) & 1][pb][sm * 32 + pp] = (unsigned int)v;
    }
    __syncthreads();   // A: th_lds[(t-1)&1] complete

    // ---- MFMA: 4 chained tiles over my 128-k quarter ----
    {
      const unsigned int* tb = &th_lds[(t - 1) & 1][c & 3][kq * 64 + o * 4];
      f32x4 acc = {0.f, 0.f, 0.f, 0.f};
#define MM(TAU)                                                            \
  {                                                                        \
    const uint4 bv = *(const uint4*)(tb + (TAU) * 16);                     \
    acc = __builtin_amdgcn_mfma_f32_16x16x32_f16(                          \
        wf##TAU, __builtin_bit_cast(half8, bv), acc, 0, 0, 0);             \
  }
      MM(0) MM(1) MM(2) MM(3)
#undef MM
      if (c < 4) {
#pragma unroll
        for (int jj = 0; jj < 4; ++jj)
          pacc[nr][c][(o << 2) + jj][kq] = acc[jj];
      }
    }
    __syncthreads();   // B: pacc ready

    // ---- epilogue: 256 lanes ----
    float th_own = 0.f;
    float y = 0.f;
    if (tid < 256) {
      const float4 pv = *(const float4*)&pacc[enr][eb][erow][0];
      y = pv.x + pv.y + pv.z + pv.w + xp;
      th_own = fast_tanh(y);
    }
    const float th_nb = __shfl_xor(th_own, 1);
    if (tid < 256) {
      if ((erow & 1) == 0) {
        const unsigned int pk = packh2(th_own, th_nb);
        const int po = (enr * 16 + erow) >> 1;           // pair 0..31
        // publish FIRST (cross-CU critical path), then local copies
        __hip_atomic_store(
            &ex[((((size_t)g * 2 + (t & 1)) * 8 + m) * 4 + eb) * 32 + po],
            ((unsigned long long)(unsigned int)t << 32) | pk,
            __ATOMIC_RELAXED, __HIP_MEMORY_SCOPE_AGENT);
        th_lds[t & 1][eb][m * 32 + po] = pk;
      }
      __builtin_nontemporal_store(y, &out[outrow_e + (size_t)t * N_ + eneuron]);
    }
    // next iteration's barrier A separates th_lds[t&1] writes from reads
  }
}

extern "C" void kernel_launch(void* const* d_in, const int* in_sizes, int n_in,
                              void* d_out, int out_size, void* d_ws, size_t ws_size,
                              hipStream_t stream) {
  const float* x   = (const float*)d_in[0];
  const float* Wih = (const float*)d_in[1];
  const float* Whh = (const float*)d_in[2];
  float* out = (float*)d_out;
  unsigned long long* ex = (unsigned long long*)d_ws;   // 256 KiB exchange
  int* ctrl = (int*)((char*)d_ws + 262144);             // 4 chunk flags

  // zero exchange tags + flags every launch (replay determinism)
  hipMemsetAsync(d_ws, 0, 262144 + 64, stream);
  rnn_fused<<<256, 1024, 0, stream>>>(x, Wih, Whh, out, ex, ctrl);
}